// Round 3
// baseline (155.959 us; speedup 1.0000x reference)
//
#include <hip/hip_runtime.h>

#define N_NODES 100000
#define D_INF   128
#define D_HID   256
#define K_CL    16
#define N_TILES (N_NODES / 16)       // 6250, exact
#define N_EDGES 3200000
#define EDGE_BLOCKS (N_EDGES / 1024) // 3125: 4 waves x 256 edges

typedef __attribute__((ext_vector_type(8))) __bf16  bf16x8;
typedef __attribute__((ext_vector_type(8))) unsigned short u16x8;
typedef __attribute__((ext_vector_type(4))) float   f32x4;
typedef __attribute__((ext_vector_type(4))) unsigned int u32x4;

__device__ __forceinline__ unsigned short f2bf(float f) {
    unsigned int u = __builtin_bit_cast(unsigned int, f);
    u += 0x7fffu + ((u >> 16) & 1u);          // RNE
    return (unsigned short)(u >> 16);
}
__device__ __forceinline__ float bflo(unsigned int p) {
    return __builtin_bit_cast(float, p << 16);
}
__device__ __forceinline__ float bfhi(unsigned int p) {
    return __builtin_bit_cast(float, p & 0xffff0000u);
}

// ---------------------------------------------------------------------------
// Prep: W1 [128][256] f32 -> W1T [256][128] bf16 ; W2 [256][16] f32 -> W2T
// [16][256] bf16. Writes coalesced.  (round-0 verbatim)
// ---------------------------------------------------------------------------
__global__ void prep_kernel(const float* __restrict__ W1,
                            const float* __restrict__ W2,
                            unsigned short* __restrict__ w1t,
                            unsigned short* __restrict__ w2t)
{
    const int i = blockIdx.x * 256 + threadIdx.x;
    if (i < D_INF * D_HID) {                  // w1t[n][k] = W1[k][n]
        const int n = i >> 7, k = i & 127;
        w1t[i] = f2bf(W1[k * D_HID + n]);
    }
    if (i < D_HID * K_CL) {                   // w2t[t][n] = W2[n][t]
        const int t = i >> 8, n = i & 255;
        w2t[i] = f2bf(W2[n * K_CL + t]);
    }
}

// ---------------------------------------------------------------------------
// Fused MLP (R2 verbatim). MFMA 16x16x32 bf16, 4 waves/block, wave = one
// 16-node tile, W1T in LDS, x prefetch one tile ahead.
// ---------------------------------------------------------------------------
#define W1S 136      // LDS row stride (bf16) for W1T
#define CHS 40       // LDS row stride (bf16) for h chunk

__global__ __launch_bounds__(256, 2) void mlp_kernel(
    const float* __restrict__ x, const unsigned short* __restrict__ W1T,
    const float* __restrict__ b1, const unsigned short* __restrict__ W2T,
    const float* __restrict__ b2, float* __restrict__ C,
    unsigned short* __restrict__ Cb)
{
    __shared__ unsigned short w1s[256 * W1S];          // 69,632 B
    __shared__ unsigned short chbuf[4][2][16 * CHS];   // 10,240 B
    __shared__ float b1s[D_HID];                       //  1,024 B -> 80,896

    const int tid  = threadIdx.x;
    const int wv   = tid >> 6;
    const int lane = tid & 63;
    const int c    = lane & 15;
    const int q    = lane >> 4;

    // ---- stage W1T into LDS (coalesced uint4 reads, b128 LDS writes) ----
    #pragma unroll
    for (int it = 0; it < 16; ++it) {
        const int idx = it * 256 + tid;        // 4096 uint4 chunks
        const int row = idx >> 4, ch = idx & 15;
        const uint4 v = ((const uint4*)W1T)[idx];
        *(uint4*)&w1s[row * W1S + ch * 8] = v;
    }
    if (tid < D_HID) b1s[tid] = b1[tid];

    // ---- loop-invariant registers: W2T fragments (32 VGPRs), b2 ----
    bf16x8 w2f[8];
    #pragma unroll
    for (int kc2 = 0; kc2 < 8; ++kc2)
        w2f[kc2] = *(const bf16x8*)(W2T + (size_t)c * D_HID + kc2 * 32 + q * 8);
    const float b2v = b2[c];
    __syncthreads();

    unsigned short* const chA = &chbuf[wv][0][0];
    unsigned short* const chB = &chbuf[wv][1][0];

    const int wid     = blockIdx.x * 4 + wv;
    const int wstride = gridDim.x * 4;

    // ---- preload first tile's raw x (8 float4 = 32 VGPRs) ----
    float4 xraw[8];
    {
        const float* xr = x + (size_t)(wid * 16 + c) * D_INF + q * 8;
        #pragma unroll
        for (int j = 0; j < 8; ++j)
            xraw[j] = *(const float4*)(xr + (j >> 1) * 32 + (j & 1) * 4);
    }

    for (int tile = wid; tile < N_TILES; tile += wstride) {
        const int m0 = tile * 16;

        // ---- issue NEXT tile's x loads first (latency overlapped) ----
        const int nxt = tile + wstride;
        float4 xnxt[8];
        if (nxt < N_TILES) {
            const float* xr = x + (size_t)(nxt * 16 + c) * D_INF + q * 8;
            #pragma unroll
            for (int j = 0; j < 8; ++j)
                xnxt[j] = *(const float4*)(xr + (j >> 1) * 32 + (j & 1) * 4);
        }

        // ---- convert CURRENT tile's preloaded x -> A fragments ----
        bf16x8 afr[4];
        #pragma unroll
        for (int kc = 0; kc < 4; ++kc) {
            const float4 xa = xraw[kc * 2], xb = xraw[kc * 2 + 1];
            u16x8 af;
            af[0] = f2bf(xa.x); af[1] = f2bf(xa.y); af[2] = f2bf(xa.z); af[3] = f2bf(xa.w);
            af[4] = f2bf(xb.x); af[5] = f2bf(xb.y); af[6] = f2bf(xb.z); af[7] = f2bf(xb.w);
            afr[kc] = __builtin_bit_cast(bf16x8, af);
        }

        // ---- fused GEMM1 -> h chunk -> GEMM2, one nt-pair at a time ----
        f32x4 acc2 = (f32x4){0.f, 0.f, 0.f, 0.f};
        #pragma unroll
        for (int kc2 = 0; kc2 < 8; ++kc2) {
            unsigned short* const cb = (kc2 & 1) ? chB : chA;
            #pragma unroll
            for (int half = 0; half < 2; ++half) {
                const int nt = kc2 * 2 + half;
                f32x4 a1 = (f32x4){0.f, 0.f, 0.f, 0.f};
                #pragma unroll
                for (int kc = 0; kc < 4; ++kc) {
                    const bf16x8 bf =
                        *(const bf16x8*)&w1s[(nt * 16 + c) * W1S + kc * 32 + q * 8];
                    a1 = __builtin_amdgcn_mfma_f32_16x16x32_bf16(afr[kc], bf, a1, 0, 0, 0);
                }
                const float bv = b1s[nt * 16 + c];
                #pragma unroll
                for (int r = 0; r < 4; ++r)
                    cb[(4 * q + r) * CHS + half * 16 + c] =
                        f2bf(fmaxf(a1[r] + bv, 0.f));
            }
            const bf16x8 a2 = *(const bf16x8*)&cb[c * CHS + q * 8];
            acc2 = __builtin_amdgcn_mfma_f32_16x16x32_bf16(a2, w2f[kc2], acc2, 0, 0, 0);
        }

        // ---- softmax per row m = 4q+r across 16 c-lanes; dual store ----
        #pragma unroll
        for (int r = 0; r < 4; ++r) {
            const float l = acc2[r] + b2v;
            float mx = l;
            mx = fmaxf(mx, __shfl_xor(mx, 1));
            mx = fmaxf(mx, __shfl_xor(mx, 2));
            mx = fmaxf(mx, __shfl_xor(mx, 4));
            mx = fmaxf(mx, __shfl_xor(mx, 8));
            const float e = __expf(l - mx);
            float sm = e;
            sm += __shfl_xor(sm, 1);
            sm += __shfl_xor(sm, 2);
            sm += __shfl_xor(sm, 4);
            sm += __shfl_xor(sm, 8);
            const float p = e / sm;
            const size_t o = (size_t)(m0 + 4 * q + r) * K_CL + c;
            C[o]  = p;
            Cb[o] = f2bf(p);
        }

        // ---- rotate prefetched x into place ----
        if (nxt < N_TILES) {
            #pragma unroll
            for (int j = 0; j < 8; ++j) xraw[j] = xnxt[j];
        }
    }
}

// ---------------------------------------------------------------------------
// Edge reduction v3 -- L1-bypass gathers (sc0).
// R1 vs R2 post-mortem: ~54 and ~200 theoretical outstanding gathers/CU both
// measured the SAME 0.27 lines/cyc/CU -> shared per-CU limiter = L1/TCP
// outstanding-miss tracking (~65 line-fills ~= 0.27 x 240cyc L2 latency).
// Fix attempt: agent-scope (sc0) loads bypass L1 allocation while keeping L2
// residency (NOT nt, which would make L2 evict-first and kill the 94% L2 hit
// rate on the 3.2MB Cb table). Inline asm since HIP has no sc0-only
// spelling; all 16 loads issued back-to-back (16-deep/wave), one manual
// vmcnt(0) fenced with sched_barrier(0) on both sides (rule #18: reg-only
// FMAs otherwise hoist past an asm waitcnt).
// ---------------------------------------------------------------------------
__global__ __launch_bounds__(256, 5) void edge_kernel(
    const int* __restrict__ ei, const unsigned short* __restrict__ Cb,
    float* __restrict__ partials)
{
    __shared__ float red[4];
    const int tid  = threadIdx.x;
    const int lane = tid & 63;
    const int wv   = tid >> 6;
    const int base = (blockIdx.x * 4 + wv) * 256;

    int u[4], v[4];
    #pragma unroll
    for (int j = 0; j < 4; ++j) {
        u[j] = ei[base + j * 64 + lane];
        v[j] = ei[N_EDGES + base + j * 64 + lane];
    }

    const int half8 = (lane & 1) * 8;    // which 16 B of the 32 B row
    const int sl    = lane >> 1;

    // ---- hoist all 16 broadcast indices ----
    int ue[8], ve[8];
    #pragma unroll
    for (int g = 0; g < 8; ++g) {
        const int src = (g & 1) * 32 + sl;
        ue[g] = __shfl(u[g >> 1], src);
        ve[g] = __shfl(v[g >> 1], src);
    }

    // ---- issue all 16 sc0 gathers (L1 bypass), then one wait ----
    u32x4 A[8], B[8];
    #pragma unroll
    for (int g = 0; g < 8; ++g) {
        const unsigned short* pa = Cb + (size_t)ue[g] * K_CL + half8;
        const unsigned short* pb = Cb + (size_t)ve[g] * K_CL + half8;
        asm volatile("global_load_dwordx4 %0, %1, off sc0"
                     : "=v"(A[g]) : "v"(pa));
        asm volatile("global_load_dwordx4 %0, %1, off sc0"
                     : "=v"(B[g]) : "v"(pb));
    }
    __builtin_amdgcn_sched_barrier(0);
    asm volatile("s_waitcnt vmcnt(0)" ::: "memory");
    __builtin_amdgcn_sched_barrier(0);

    float s0 = 0.f, s1 = 0.f, s2 = 0.f, s3 = 0.f;
    #pragma unroll
    for (int g = 0; g < 8; ++g) {
        const u32x4 a = A[g], b = B[g];
        float t = 0.f;                   // per-g chain (8 fma), merged below
        t = fmaf(bflo(a[0]), bflo(b[0]), t);
        t = fmaf(bfhi(a[0]), bfhi(b[0]), t);
        t = fmaf(bflo(a[1]), bflo(b[1]), t);
        t = fmaf(bfhi(a[1]), bfhi(b[1]), t);
        t = fmaf(bflo(a[2]), bflo(b[2]), t);
        t = fmaf(bfhi(a[2]), bfhi(b[2]), t);
        t = fmaf(bflo(a[3]), bflo(b[3]), t);
        t = fmaf(bfhi(a[3]), bfhi(b[3]), t);
        if ((g & 3) == 0) s0 += t;
        else if ((g & 3) == 1) s1 += t;
        else if ((g & 3) == 2) s2 += t;
        else s3 += t;
    }
    float s = (s0 + s1) + (s2 + s3);

    s += __shfl_xor(s, 1);
    s += __shfl_xor(s, 2);
    s += __shfl_xor(s, 4);
    s += __shfl_xor(s, 8);
    s += __shfl_xor(s, 16);
    s += __shfl_xor(s, 32);
    if (lane == 0) red[wv] = s;
    __syncthreads();
    if (tid == 0) partials[blockIdx.x] = red[0] + red[1] + red[2] + red[3];
}

// ---------------------------------------------------------------------------
// Finalize: reduce 3125 block partials, write -sum/E.  (round-0 verbatim;
// single-address device atomics from 3125 blocks cost +15us in R1 -- keep
// the separate 2us reduction kernel.)
// ---------------------------------------------------------------------------
__global__ __launch_bounds__(256) void finalize_kernel(
    const float* __restrict__ partials, float* __restrict__ out)
{
    __shared__ float red[4];
    const int tid = threadIdx.x;
    float s = 0.f;
    for (int i = tid; i < EDGE_BLOCKS; i += 256) s += partials[i];
    s += __shfl_xor(s, 1);
    s += __shfl_xor(s, 2);
    s += __shfl_xor(s, 4);
    s += __shfl_xor(s, 8);
    s += __shfl_xor(s, 16);
    s += __shfl_xor(s, 32);
    if ((tid & 63) == 0) red[tid >> 6] = s;
    __syncthreads();
    if (tid == 0)
        out[(size_t)N_NODES * K_CL] =
            -(red[0] + red[1] + red[2] + red[3]) / (float)N_EDGES;
}

// ---------------------------------------------------------------------------
extern "C" void kernel_launch(void* const* d_in, const int* in_sizes, int n_in,
                              void* d_out, int out_size, void* d_ws, size_t ws_size,
                              hipStream_t stream) {
    const float* x  = (const float*)d_in[0];
    const int*   ei = (const int*)  d_in[1];
    const float* W1 = (const float*)d_in[2];
    const float* b1 = (const float*)d_in[3];
    const float* W2 = (const float*)d_in[4];
    const float* b2 = (const float*)d_in[5];
    float* out = (float*)d_out;

    // ws: W1T bf16 @0 (64 KB), W2T bf16 @65536 (8 KB),
    //     Cb bf16 [100000*16] @73760 (3.2 MB), partials f32 @3273760 (12.5 KB)
    unsigned short* w1t      = (unsigned short*)d_ws;
    unsigned short* w2t      = (unsigned short*)((char*)d_ws + 65536);
    unsigned short* Cb       = (unsigned short*)((char*)d_ws + 73760);
    float*          partials = (float*)((char*)d_ws + 3273760);

    prep_kernel<<<128, 256, 0, stream>>>(W1, W2, w1t, w2t);
    mlp_kernel<<<512, 256, 0, stream>>>(x, w1t, b1, w2t, b2, out, Cb);
    edge_kernel<<<EDGE_BLOCKS, 256, 0, stream>>>(ei, Cb, partials);
    finalize_kernel<<<1, 256, 0, stream>>>(partials, out);
}

// Round 4
// 151.525 us; speedup vs baseline: 1.0293x; 1.0293x over previous
//
#include <hip/hip_runtime.h>

#define N_NODES 100000
#define D_INF   128
#define D_HID   256
#define K_CL    16
#define N_TILES (N_NODES / 16)       // 6250, exact
#define N_EDGES 3200000
#define EDGE_BLOCKS (N_EDGES / 1024) // 3125: 4 waves x 256 edges

typedef __attribute__((ext_vector_type(8))) __bf16  bf16x8;
typedef __attribute__((ext_vector_type(8))) unsigned short u16x8;
typedef __attribute__((ext_vector_type(4))) float   f32x4;
typedef __attribute__((ext_vector_type(2))) float   f32x2;
typedef __attribute__((ext_vector_type(4))) unsigned int u32x4;

__device__ __forceinline__ unsigned short f2bf(float f) {
    unsigned int u = __builtin_bit_cast(unsigned int, f);
    u += 0x7fffu + ((u >> 16) & 1u);          // RNE
    return (unsigned short)(u >> 16);
}

// ---------------------------------------------------------------------------
// Prep: W1 [128][256] f32 -> W1T [256][128] bf16 ; W2 [256][16] f32 -> W2T
// [16][256] bf16. Writes coalesced.  (round-0 verbatim)
// ---------------------------------------------------------------------------
__global__ void prep_kernel(const float* __restrict__ W1,
                            const float* __restrict__ W2,
                            unsigned short* __restrict__ w1t,
                            unsigned short* __restrict__ w2t)
{
    const int i = blockIdx.x * 256 + threadIdx.x;
    if (i < D_INF * D_HID) {                  // w1t[n][k] = W1[k][n]
        const int n = i >> 7, k = i & 127;
        w1t[i] = f2bf(W1[k * D_HID + n]);
    }
    if (i < D_HID * K_CL) {                   // w2t[t][n] = W2[n][t]
        const int t = i >> 8, n = i & 255;
        w2t[i] = f2bf(W2[n * K_CL + t]);
    }
}

// ---------------------------------------------------------------------------
// Fused MLP (R2 structure). MFMA 16x16x32 bf16, 4 waves/block, wave = one
// 16-node tile, W1T in LDS, x prefetch one tile ahead. Only change this
// round: the loss-path copy of C is stored as fp8 e4m3 (1 byte/elem,
// v_cvt_pk_fp8_f32) instead of bf16 -- halves the edge kernel's gather
// address count (see edge_kernel comment).
// ---------------------------------------------------------------------------
#define W1S 136      // LDS row stride (bf16) for W1T
#define CHS 40       // LDS row stride (bf16) for h chunk

__global__ __launch_bounds__(256, 2) void mlp_kernel(
    const float* __restrict__ x, const unsigned short* __restrict__ W1T,
    const float* __restrict__ b1, const unsigned short* __restrict__ W2T,
    const float* __restrict__ b2, float* __restrict__ C,
    unsigned char* __restrict__ C8)
{
    __shared__ unsigned short w1s[256 * W1S];          // 69,632 B
    __shared__ unsigned short chbuf[4][2][16 * CHS];   // 10,240 B
    __shared__ float b1s[D_HID];                       //  1,024 B -> 80,896

    const int tid  = threadIdx.x;
    const int wv   = tid >> 6;
    const int lane = tid & 63;
    const int c    = lane & 15;
    const int q    = lane >> 4;

    // ---- stage W1T into LDS (coalesced uint4 reads, b128 LDS writes) ----
    #pragma unroll
    for (int it = 0; it < 16; ++it) {
        const int idx = it * 256 + tid;        // 4096 uint4 chunks
        const int row = idx >> 4, ch = idx & 15;
        const uint4 v = ((const uint4*)W1T)[idx];
        *(uint4*)&w1s[row * W1S + ch * 8] = v;
    }
    if (tid < D_HID) b1s[tid] = b1[tid];

    // ---- loop-invariant registers: W2T fragments (32 VGPRs), b2 ----
    bf16x8 w2f[8];
    #pragma unroll
    for (int kc2 = 0; kc2 < 8; ++kc2)
        w2f[kc2] = *(const bf16x8*)(W2T + (size_t)c * D_HID + kc2 * 32 + q * 8);
    const float b2v = b2[c];
    __syncthreads();

    unsigned short* const chA = &chbuf[wv][0][0];
    unsigned short* const chB = &chbuf[wv][1][0];

    const int wid     = blockIdx.x * 4 + wv;
    const int wstride = gridDim.x * 4;

    // ---- preload first tile's raw x (8 float4 = 32 VGPRs) ----
    float4 xraw[8];
    {
        const float* xr = x + (size_t)(wid * 16 + c) * D_INF + q * 8;
        #pragma unroll
        for (int j = 0; j < 8; ++j)
            xraw[j] = *(const float4*)(xr + (j >> 1) * 32 + (j & 1) * 4);
    }

    for (int tile = wid; tile < N_TILES; tile += wstride) {
        const int m0 = tile * 16;

        // ---- issue NEXT tile's x loads first (latency overlapped) ----
        const int nxt = tile + wstride;
        float4 xnxt[8];
        if (nxt < N_TILES) {
            const float* xr = x + (size_t)(nxt * 16 + c) * D_INF + q * 8;
            #pragma unroll
            for (int j = 0; j < 8; ++j)
                xnxt[j] = *(const float4*)(xr + (j >> 1) * 32 + (j & 1) * 4);
        }

        // ---- convert CURRENT tile's preloaded x -> A fragments ----
        bf16x8 afr[4];
        #pragma unroll
        for (int kc = 0; kc < 4; ++kc) {
            const float4 xa = xraw[kc * 2], xb = xraw[kc * 2 + 1];
            u16x8 af;
            af[0] = f2bf(xa.x); af[1] = f2bf(xa.y); af[2] = f2bf(xa.z); af[3] = f2bf(xa.w);
            af[4] = f2bf(xb.x); af[5] = f2bf(xb.y); af[6] = f2bf(xb.z); af[7] = f2bf(xb.w);
            afr[kc] = __builtin_bit_cast(bf16x8, af);
        }

        // ---- fused GEMM1 -> h chunk -> GEMM2, one nt-pair at a time ----
        f32x4 acc2 = (f32x4){0.f, 0.f, 0.f, 0.f};
        #pragma unroll
        for (int kc2 = 0; kc2 < 8; ++kc2) {
            unsigned short* const cb = (kc2 & 1) ? chB : chA;
            #pragma unroll
            for (int half = 0; half < 2; ++half) {
                const int nt = kc2 * 2 + half;
                f32x4 a1 = (f32x4){0.f, 0.f, 0.f, 0.f};
                #pragma unroll
                for (int kc = 0; kc < 4; ++kc) {
                    const bf16x8 bf =
                        *(const bf16x8*)&w1s[(nt * 16 + c) * W1S + kc * 32 + q * 8];
                    a1 = __builtin_amdgcn_mfma_f32_16x16x32_bf16(afr[kc], bf, a1, 0, 0, 0);
                }
                const float bv = b1s[nt * 16 + c];
                #pragma unroll
                for (int r = 0; r < 4; ++r)
                    cb[(4 * q + r) * CHS + half * 16 + c] =
                        f2bf(fmaxf(a1[r] + bv, 0.f));
            }
            const bf16x8 a2 = *(const bf16x8*)&cb[c * CHS + q * 8];
            acc2 = __builtin_amdgcn_mfma_f32_16x16x32_bf16(a2, w2f[kc2], acc2, 0, 0, 0);
        }

        // ---- softmax per row m = 4q+r across 16 c-lanes; dual store ----
        #pragma unroll
        for (int r = 0; r < 4; ++r) {
            const float l = acc2[r] + b2v;
            float mx = l;
            mx = fmaxf(mx, __shfl_xor(mx, 1));
            mx = fmaxf(mx, __shfl_xor(mx, 2));
            mx = fmaxf(mx, __shfl_xor(mx, 4));
            mx = fmaxf(mx, __shfl_xor(mx, 8));
            const float e = __expf(l - mx);
            float sm = e;
            sm += __shfl_xor(sm, 1);
            sm += __shfl_xor(sm, 2);
            sm += __shfl_xor(sm, 4);
            sm += __shfl_xor(sm, 8);
            const float p = e / sm;
            const size_t o = (size_t)(m0 + 4 * q + r) * K_CL + c;
            C[o]  = p;
            // fp8 e4m3 copy for the edge gather (native cvt, RNE)
            C8[o] = (unsigned char)
                (__builtin_amdgcn_cvt_pk_fp8_f32(p, p, 0, false) & 0xff);
        }

        // ---- rotate prefetched x into place ----
        if (nxt < N_TILES) {
            #pragma unroll
            for (int j = 0; j < 8; ++j) xraw[j] = xnxt[j];
        }
    }
}

// ---------------------------------------------------------------------------
// Edge reduction v4 -- fp8 rows: ONE lane-address per edge-side.
// R1/R2/R3 established the gather wall (~0.27 lines/cyc/CU) is insensitive
// to window depth, occupancy, and L1 scope -> TA address throughput:
// a wave64 scattered gather costs ~1 cyc per lane-address in the texture
// address unit, so 12.8M lane-addresses ~= 21us of pure TA occupancy.
// fp8 rows are 16 B -> one dwordx4 per edge-side: 6.4M addresses (2x fewer
// gather instrs), and the shfl-broadcast stage disappears (each lane owns
// its 4 edges end-to-end). Unpack via native v_cvt_pk_f32_fp8.
// Pre-committed read: if this is neutral, the wall is L2-side line-request
// service (invariant at 6.4M) -> structural floor -> roofline.
// ---------------------------------------------------------------------------
__global__ __launch_bounds__(256, 5) void edge_kernel(
    const int* __restrict__ ei, const unsigned char* __restrict__ C8,
    float* __restrict__ partials)
{
    __shared__ float red[4];
    const int tid  = threadIdx.x;
    const int lane = tid & 63;
    const int wv   = tid >> 6;
    const int base = (blockIdx.x * 4 + wv) * 256;

    // coalesced index loads: 4 edges per lane, no broadcast needed
    int u[4], v[4];
    #pragma unroll
    for (int j = 0; j < 4; ++j) {
        u[j] = ei[base + j * 64 + lane];
        v[j] = ei[N_EDGES + base + j * 64 + lane];
    }

    // 8 independent 16B gathers, all in flight together (32 VGPRs)
    u32x4 A[4], B[4];
    #pragma unroll
    for (int j = 0; j < 4; ++j) {
        A[j] = *(const u32x4*)(C8 + (size_t)u[j] * 16);
        B[j] = *(const u32x4*)(C8 + (size_t)v[j] * 16);
    }

    float s0 = 0.f, s1 = 0.f, s2 = 0.f, s3 = 0.f;
    #pragma unroll
    for (int j = 0; j < 4; ++j) {
        float t = 0.f;
        #pragma unroll
        for (int d = 0; d < 4; ++d) {
            const f32x2 a0 = __builtin_amdgcn_cvt_pk_f32_fp8(A[j][d], false);
            const f32x2 a1 = __builtin_amdgcn_cvt_pk_f32_fp8(A[j][d], true);
            const f32x2 b0 = __builtin_amdgcn_cvt_pk_f32_fp8(B[j][d], false);
            const f32x2 b1 = __builtin_amdgcn_cvt_pk_f32_fp8(B[j][d], true);
            t = fmaf(a0[0], b0[0], t);
            t = fmaf(a0[1], b0[1], t);
            t = fmaf(a1[0], b1[0], t);
            t = fmaf(a1[1], b1[1], t);
        }
        if (j == 0) s0 = t; else if (j == 1) s1 = t;
        else if (j == 2) s2 = t; else s3 = t;
    }
    float s = (s0 + s1) + (s2 + s3);

    s += __shfl_xor(s, 1);
    s += __shfl_xor(s, 2);
    s += __shfl_xor(s, 4);
    s += __shfl_xor(s, 8);
    s += __shfl_xor(s, 16);
    s += __shfl_xor(s, 32);
    if (lane == 0) red[wv] = s;
    __syncthreads();
    if (tid == 0) partials[blockIdx.x] = red[0] + red[1] + red[2] + red[3];
}

// ---------------------------------------------------------------------------
// Finalize: reduce 3125 block partials, write -sum/E.  (round-0 verbatim;
// single-address device atomics from 3125 blocks cost +15us in R1 -- keep
// the separate 2us reduction kernel.)
// ---------------------------------------------------------------------------
__global__ __launch_bounds__(256) void finalize_kernel(
    const float* __restrict__ partials, float* __restrict__ out)
{
    __shared__ float red[4];
    const int tid = threadIdx.x;
    float s = 0.f;
    for (int i = tid; i < EDGE_BLOCKS; i += 256) s += partials[i];
    s += __shfl_xor(s, 1);
    s += __shfl_xor(s, 2);
    s += __shfl_xor(s, 4);
    s += __shfl_xor(s, 8);
    s += __shfl_xor(s, 16);
    s += __shfl_xor(s, 32);
    if ((tid & 63) == 0) red[tid >> 6] = s;
    __syncthreads();
    if (tid == 0)
        out[(size_t)N_NODES * K_CL] =
            -(red[0] + red[1] + red[2] + red[3]) / (float)N_EDGES;
}

// ---------------------------------------------------------------------------
extern "C" void kernel_launch(void* const* d_in, const int* in_sizes, int n_in,
                              void* d_out, int out_size, void* d_ws, size_t ws_size,
                              hipStream_t stream) {
    const float* x  = (const float*)d_in[0];
    const int*   ei = (const int*)  d_in[1];
    const float* W1 = (const float*)d_in[2];
    const float* b1 = (const float*)d_in[3];
    const float* W2 = (const float*)d_in[4];
    const float* b2 = (const float*)d_in[5];
    float* out = (float*)d_out;

    // ws: W1T bf16 @0 (64 KB), W2T bf16 @65536 (8 KB),
    //     C8 fp8 [100000*16] @73760 (1.6 MB), partials f32 @1673760 (12.5 KB)
    unsigned short* w1t      = (unsigned short*)d_ws;
    unsigned short* w2t      = (unsigned short*)((char*)d_ws + 65536);
    unsigned char*  C8       = (unsigned char*)((char*)d_ws + 73760);
    float*          partials = (float*)((char*)d_ws + 1673760);

    prep_kernel<<<128, 256, 0, stream>>>(W1, W2, w1t, w2t);
    mlp_kernel<<<512, 256, 0, stream>>>(x, w1t, b1, w2t, b2, out, C8);
    edge_kernel<<<EDGE_BLOCKS, 256, 0, stream>>>(ei, C8, partials);
    finalize_kernel<<<1, 256, 0, stream>>>(partials, out);
}